// Round 9
// baseline (151.084 us; speedup 1.0000x reference)
//
#include <hip/hip_runtime.h>

// RoI max pooling forward — cell-major with register accumulators.
// x: (1, 512, 50, 50) f32; rois: (N,5) f32; out: (N,512,7,7) f32
//
// R6-R8 lesson: per-bin global-load structure (bounds read + readfirstlane +
// clamped 2x2 loads per bin) stalled ~55-65us regardless of MLP tweaks.
// R9 inverts: h-bounds depend only on ph, w-bounds only on pw (7+7, not 49).
// A wave owns 1-2 ph-rows, keeps all 7 pw accumulators in registers
// (pw fully unrolled -> static indexing), sweeps the roi cells once:
// 1 coalesced float2 load + 1 fmax per cell-touch. No per-bin overhead.
//
// Bounds math bit-matches XLA: roi * (1.0f/7.0f) reciprocal multiply (NOT
// true division), rintf (round-half-even), *0.0625f exact, clip to [0,H].

#define HH 50
#define WW 50
#define CC 512
#define OH 7
#define OW 7
#define NBINS 49
#define HW (HH * WW)
#define CG 128

// Per-dimension bin bounds, exact XLA numerics (same ops as verified R4-R8).
__device__ __forceinline__ int2 dim_bounds(float lo_px, float hi_px, int p,
                                           int limit) {
    const float RCP7 = 1.0f / 7.0f;  // XLA's reciprocal for /7
    int s = (int)rintf(lo_px * 0.0625f);
    int e = (int)rintf(hi_px * 0.0625f);
    float span = (float)max(e - s + 1, 1);
    float bin  = span * RCP7;
    int b0 = min(max((int)floorf(bin * (float)p) + s, 0), limit);
    int b1 = min(max((int)ceilf (bin * (float)(p + 1)) + s, 0), limit);
    return make_int2(b0, b1);
}

__device__ __forceinline__ int4 compute_bounds(const float* __restrict__ r,
                                               int ph, int pw) {
    int2 hb = dim_bounds(r[2], r[4], ph, HH);
    int2 wb = dim_bounds(r[1], r[3], pw, WW);
    return make_int4(hb.x, hb.y, wb.x, wb.y);
}

// Kernel A: x (C, HW) -> xt (HW, C), 64x64 LDS-tiled, both sides coalesced.
__global__ __launch_bounds__(256) void transpose_x(const float* __restrict__ x,
                                                   float* __restrict__ xt) {
    __shared__ float tile[64][65];
    int tx = threadIdx.x & 63;
    int tg = threadIdx.x >> 6;  // 0..3
    int hw0 = blockIdx.x * 64;
    int c0  = blockIdx.y * 64;
    #pragma unroll
    for (int i = 0; i < 16; ++i) {
        int r  = tg * 16 + i;        // c offset in tile
        int hw = hw0 + tx;
        if (hw < HW) tile[r][tx] = x[(size_t)(c0 + r) * HW + hw];
    }
    __syncthreads();
    #pragma unroll
    for (int i = 0; i < 16; ++i) {
        int r  = tg * 16 + i;        // hw offset in tile
        int hw = hw0 + r;
        if (hw < HW) xt[(size_t)hw * CC + c0 + tx] = tile[tx][r];
    }
}

// Kernel B: block = (n, cgroup of 128 ch); wave = ph-row(s); lane = ch pair.
__global__ __launch_bounds__(256) void roi_pool_cells(
    const float* __restrict__ xt, const float* __restrict__ rois,
    float* __restrict__ out)
{
    __shared__ int2  shb[OH], swb[OW];
    __shared__ float stile[CG * NBINS];  // [c_local][bin] — out layout
    int tid = threadIdx.x;
    int n   = blockIdx.x >> 2;           // CC/CG = 4 cgroups
    int cg  = blockIdx.x & 3;

    const float* r = rois + (size_t)n * 5;
    if (tid < OH)                         shb[tid]     = dim_bounds(r[2], r[4], tid, HH);
    else if (tid >= 8 && tid < 8 + OW)    swb[tid - 8] = dim_bounds(r[1], r[3], tid - 8, WW);
    __syncthreads();

    int lane = tid & 63;
    int wv   = tid >> 6;
    const float* base = xt + cg * CG + lane * 2;  // 8B-aligned float2 lane slot

    for (int phi = 0; phi < 2; ++phi) {
        int ph = wv + phi * 4;           // waves 0..3 -> rows {0,4},{1,5},{2,6},{3}
        if (ph >= OH) break;
        int2 hb = shb[ph];
        int h0 = __builtin_amdgcn_readfirstlane(hb.x);
        int h1 = __builtin_amdgcn_readfirstlane(hb.y);

        float2 acc[OW];
        #pragma unroll
        for (int pw = 0; pw < OW; ++pw) { acc[pw].x = -INFINITY; acc[pw].y = -INFINITY; }

        #pragma unroll
        for (int pw = 0; pw < OW; ++pw) {   // compile-time -> static acc index
            int2 wb = swb[pw];
            int w0 = __builtin_amdgcn_readfirstlane(wb.x);
            int w1 = __builtin_amdgcn_readfirstlane(wb.y);
            for (int h = h0; h < h1; ++h) {
                const float* rowp = base + (size_t)(h * WW) * CC;
                for (int w = w0; w < w1; ++w) {
                    float2 v = *(const float2*)&rowp[(size_t)w * CC];
                    acc[pw].x = fmaxf(acc[pw].x, v.x);
                    acc[pw].y = fmaxf(acc[pw].y, v.y);
                }
            }
        }

        #pragma unroll
        for (int pw = 0; pw < OW; ++pw) {
            int2 wb = swb[pw];
            bool ne = (h0 < h1) && (wb.x < wb.y);
            int bin = ph * OW + pw;
            stile[(lane * 2 + 0) * NBINS + bin] = ne ? acc[pw].x : 0.0f;
            stile[(lane * 2 + 1) * NBINS + bin] = ne ? acc[pw].y : 0.0f;
        }
    }
    __syncthreads();

    // 128*49 = 6272 contiguous floats = this block's exact out slice.
    size_t ob4 = (((size_t)n * CC + cg * CG) * NBINS) >> 2;
    float4* o4 = (float4*)out;
    const float4* s4 = (const float4*)stile;
    for (int t = tid; t < (CG * NBINS) / 4; t += 256)
        o4[ob4 + t] = s4[t];
}

// Fallback (ws too small for xt): R4's verified one-thread-per-output kernel.
__global__ __launch_bounds__(256) void roi_pool_fused(const float* __restrict__ x,
                                                      const float* __restrict__ rois,
                                                      float* __restrict__ out,
                                                      int total) {
    int idx = blockIdx.x * blockDim.x + threadIdx.x;
    if (idx >= total) return;
    int pw = idx % OW;
    int t  = idx / OW;
    int ph = t % OH;
    t /= OH;
    int c = t % CC;
    int n = t / CC;
    const float* r = rois + (size_t)n * 5;
    int4 bnd = compute_bounds(r, ph, pw);
    int b = (int)r[0];
    const float* plane = x + ((size_t)b * CC + c) * HW;
    float m = -INFINITY;
    for (int h = bnd.x; h < bnd.y; ++h) {
        const float* row = plane + h * WW;
        for (int w = bnd.z; w < bnd.w; ++w)
            m = fmaxf(m, row[w]);
    }
    bool nonempty = (bnd.x < bnd.y) && (bnd.z < bnd.w);
    out[idx] = nonempty ? m : 0.0f;
}

extern "C" void kernel_launch(void* const* d_in, const int* in_sizes, int n_in,
                              void* d_out, int out_size, void* d_ws, size_t ws_size,
                              hipStream_t stream) {
    const float* x    = (const float*)d_in[0];
    const float* rois = (const float*)d_in[1];
    float* out = (float*)d_out;
    int nrois = in_sizes[1] / 5;

    size_t need = (size_t)HW * CC * sizeof(float);  // 5.12 MB for xt
    if (ws_size >= need) {
        float* xt = (float*)d_ws;
        transpose_x<<<dim3((HW + 63) / 64, CC / 64), 256, 0, stream>>>(x, xt);
        roi_pool_cells<<<nrois * (CC / CG), 256, 0, stream>>>(xt, rois, out);
    } else {
        roi_pool_fused<<<(out_size + 255) / 256, 256, 0, stream>>>(x, rois, out,
                                                                   out_size);
    }
}